// Round 1
// baseline (2759.614 us; speedup 1.0000x reference)
//
#include <hip/hip_runtime.h>
#include <math.h>
#include <float.h>

// Problem constants
#define BB    64
#define CCH   256
#define KKE   1024
#define HWN   1024
#define NTOT  (BB*HWN)          // 65536
#define OUT_ELE (BB*CCH*HWN)    // 16777216
// d_out layout (floats): loss | out | perplexity | encodings
#define LOSS_OFF 0
#define OUT_OFF  1
#define PERP_OFF (1 + OUT_ELE)           // 16777217
#define ENC_OFF  (2 + OUT_ELE)           // 16777218 (byte off % 16 == 8 -> float2 stores only)

// workspace layout (bytes)
#define WS_IDX   0                        // int32[65536]
#define WS_HIST  (NTOT*4)                 // uint32[1024]
#define WS_BNORM (WS_HIST + KKE*4)        // float[1024]
#define WS_LOSS  (WS_BNORM + KKE*4)       // float[1]
#define WS_EMBT  524288                   // float[256*1024] transposed emb

// ---------------- Kernel 1: transpose emb, ||e_k||^2 (fp64), zero accumulators
__global__ __launch_bounds__(256) void prep_kernel(const float* __restrict__ emb,
                                                   float* __restrict__ embT,
                                                   float* __restrict__ bnorm,
                                                   unsigned int* __restrict__ hist,
                                                   float* __restrict__ lossacc) {
    const int k = blockIdx.x;     // 0..1023
    const int t = threadIdx.x;    // 0..255 = c
    float v = emb[k*CCH + t];
    embT[(size_t)t*KKE + k] = v;
    double sq = (double)v * (double)v;
    #pragma unroll
    for (int off = 32; off; off >>= 1) sq += __shfl_down(sq, off);
    __shared__ double wred[4];
    const int wave = t >> 6, lane = t & 63;
    if (lane == 0) wred[wave] = sq;
    __syncthreads();
    if (t == 0) bnorm[k] = (float)(wred[0] + wred[1] + wred[2] + wred[3]);
    if (blockIdx.x < 4) hist[blockIdx.x*256 + t] = 0u;
    if (blockIdx.x == 4 && t == 0) *lossacc = 0.0f;
}

// ---------------- Kernel 2: fused distance GEMM + argmin
// Block: 256 threads -> 128n x 128k tile, 8x8 per thread. K-loop (8 tiles of 128
// codes) inside the block so argmin stays in registers. grid = (8 n-tiles, 64 b).
__global__ __launch_bounds__(256, 2) void argmin_kernel(const float* __restrict__ inp,
                                                        const float* __restrict__ embT,
                                                        const float* __restrict__ bnorm,
                                                        int* __restrict__ idx) {
    __shared__ float As[16][128];     // A^T chunk: [cc][nn]
    __shared__ float Es[16][136];     // embT chunk: [cc][kk], padded row (544B, 16B-aligned)
    __shared__ float aS[128];         // ||x_n||^2 for the tile
    __shared__ float bS[128];         // ||e_k||^2 for current k-tile
    __shared__ float red_d[128][17];
    __shared__ int   red_k[128][17];

    const int t  = threadIdx.x;
    const int tn = t & 15;            // 0..15
    const int tk = t >> 4;            // 0..15
    const int b  = blockIdx.y;
    const int n0 = blockIdx.x * 128;
    const float* gA = inp + (size_t)b*CCH*HWN + n0;   // gA[c*1024 + nn]

    double an[8] = {0,0,0,0,0,0,0,0};  // fp64 ||x||^2, only tk==0 threads use it
    float bestd[8];
    int   bestk[8];
    #pragma unroll
    for (int i = 0; i < 8; ++i) { bestd[i] = FLT_MAX; bestk[i] = 0; }

    for (int kt = 0; kt < 8; ++kt) {
        const int k0 = kt * 128;
        float acc[8][8];
        #pragma unroll
        for (int i = 0; i < 8; ++i)
            #pragma unroll
            for (int j = 0; j < 8; ++j) acc[i][j] = 0.0f;

        for (int ct = 0; ct < 16; ++ct) {
            const int c0 = ct * 16;
            __syncthreads();   // protect LDS from previous compute/readers
            #pragma unroll
            for (int i = 0; i < 2; ++i) {          // A tile: 16x128 via float4
                int f = i*256 + t; int cc = f >> 5; int q = f & 31;
                *(float4*)&As[cc][q*4] =
                    *(const float4*)&gA[(size_t)(c0+cc)*HWN + q*4];
            }
            #pragma unroll
            for (int i = 0; i < 2; ++i) {          // E tile: 16x128 via float4
                int f = i*256 + t; int cc = f >> 5; int q = f & 31;
                *(float4*)&Es[cc][q*4] =
                    *(const float4*)&embT[(size_t)(c0+cc)*KKE + k0 + q*4];
            }
            if (ct == 0 && t < 128) bS[t] = bnorm[k0 + t];
            __syncthreads();

            #pragma unroll
            for (int cc = 0; cc < 16; ++cc) {
                float4 a0 = *(const float4*)&As[cc][tn*4];
                float4 a1 = *(const float4*)&As[cc][64 + tn*4];
                float4 e0 = *(const float4*)&Es[cc][tk*4];
                float4 e1 = *(const float4*)&Es[cc][64 + tk*4];
                float av[8] = {a0.x,a0.y,a0.z,a0.w,a1.x,a1.y,a1.z,a1.w};
                float ev[8] = {e0.x,e0.y,e0.z,e0.w,e1.x,e1.y,e1.z,e1.w};
                #pragma unroll
                for (int i = 0; i < 8; ++i)
                    #pragma unroll
                    for (int j = 0; j < 8; ++j)
                        acc[i][j] += av[i] * ev[j];
                if (kt == 0 && tk == 0) {
                    #pragma unroll
                    for (int i = 0; i < 8; ++i)
                        an[i] += (double)av[i] * (double)av[i];
                }
            }
        }

        if (kt == 0) {
            if (tk == 0) {
                #pragma unroll
                for (int i = 0; i < 8; ++i) {
                    int nl = (i < 4) ? tn*4 + i : 64 + tn*4 + (i - 4);
                    aS[nl] = (float)an[i];
                }
            }
            __syncthreads();
        }

        // d = fp32( fp32(a + b_k) - 2*dot ), first-index tie-break via (d==, k<)
        #pragma unroll
        for (int i = 0; i < 8; ++i) {
            int nl = (i < 4) ? tn*4 + i : 64 + tn*4 + (i - 4);
            float a = aS[nl];
            #pragma unroll
            for (int j = 0; j < 8; ++j) {
                int kl = (j < 4) ? tk*4 + j : 64 + tk*4 + (j - 4);
                float s = a + bS[kl];
                float d = s - 2.0f * acc[i][j];
                int kg = k0 + kl;
                if (d < bestd[i] || (d == bestd[i] && kg < bestk[i])) {
                    bestd[i] = d; bestk[i] = kg;
                }
            }
        }
        // next iteration's top-of-ct barrier protects bS/As/Es reuse
    }

    __syncthreads();
    #pragma unroll
    for (int i = 0; i < 8; ++i) {
        int nl = (i < 4) ? tn*4 + i : 64 + tn*4 + (i - 4);
        red_d[nl][tk] = bestd[i];
        red_k[nl][tk] = bestk[i];
    }
    __syncthreads();
    if (t < 128) {
        float bd = red_d[t][0]; int bk = red_k[t][0];
        #pragma unroll
        for (int g = 1; g < 16; ++g) {
            float d = red_d[t][g]; int k = red_k[t][g];
            if (d < bd || (d == bd && k < bk)) { bd = d; bk = k; }
        }
        idx[b*HWN + n0 + t] = bk;
    }
}

// ---------------- Kernel 3: encodings one-hot (zero + scatter fused) + histogram
__global__ __launch_bounds__(256) void onehot_kernel(const int* __restrict__ idx,
                                                     float* __restrict__ enc,
                                                     unsigned int* __restrict__ hist) {
    const int n = blockIdx.x;
    const int t = threadIdx.x;
    const int k = idx[n];                 // broadcast read
    const int j4 = t * 4;
    float2 v0 = {0.0f, 0.0f}, v1 = {0.0f, 0.0f};
    if (k == j4)     v0.x = 1.0f;
    if (k == j4 + 1) v0.y = 1.0f;
    if (k == j4 + 2) v1.x = 1.0f;
    if (k == j4 + 3) v1.y = 1.0f;
    float* row = enc + (size_t)n * KKE;
    *(float2*)&row[j4]     = v0;          // base % 16 == 8 -> float2 alignment only
    *(float2*)&row[j4 + 2] = v1;
    if (t == 0) atomicAdd(&hist[k], 1u);
}

// ---------------- Kernel 4: out = gather(e) (value of STE) + loss partial sums
__global__ __launch_bounds__(256) void out_loss_kernel(const float* __restrict__ inp,
                                                       const float* __restrict__ embT,
                                                       const int* __restrict__ idx,
                                                       float* __restrict__ out,
                                                       float* __restrict__ lossacc) {
    const int t = threadIdx.x;
    const size_t stride = (size_t)gridDim.x * 256;
    float lsum = 0.0f;
    for (size_t m = (size_t)blockIdx.x * 256 + t; m < (size_t)OUT_ELE; m += stride) {
        int hw = (int)(m & 1023);
        int c  = (int)((m >> 10) & 255);
        int b  = (int)(m >> 18);
        int k  = idx[b*HWN + hw];
        float e = embT[(size_t)c*KKE + k];  // same-row gather: L1/L2 friendly
        float x = inp[m];
        out[m] = e;
        float df = e - x;
        lsum += df * df;
    }
    #pragma unroll
    for (int off = 32; off; off >>= 1) lsum += __shfl_down(lsum, off);
    __shared__ float wred[4];
    const int wave = t >> 6, lane = t & 63;
    if (lane == 0) wred[wave] = lsum;
    __syncthreads();
    if (t == 0) atomicAdd(lossacc, wred[0] + wred[1] + wred[2] + wred[3]);
}

// ---------------- Kernel 5: finalize loss + perplexity
__global__ __launch_bounds__(1024) void final_kernel(const unsigned int* __restrict__ hist,
                                                     const float* __restrict__ lossacc,
                                                     float* __restrict__ d_out) {
    const int t = threadIdx.x;   // 0..1023 = k
    float p = (float)hist[t] * (1.0f / 65536.0f);
    float v = p * logf(p + 1e-10f);
    #pragma unroll
    for (int off = 32; off; off >>= 1) v += __shfl_down(v, off);
    __shared__ float wred[16];
    const int wave = t >> 6, lane = t & 63;
    if (lane == 0) wred[wave] = v;
    __syncthreads();
    if (t == 0) {
        float s = 0.0f;
        #pragma unroll
        for (int i = 0; i < 16; ++i) s += wred[i];
        d_out[PERP_OFF] = expf(-s);
        d_out[LOSS_OFF] = 1.25f * (*lossacc) * (1.0f / (float)OUT_ELE);
    }
}

extern "C" void kernel_launch(void* const* d_in, const int* in_sizes, int n_in,
                              void* d_out, int out_size, void* d_ws, size_t ws_size,
                              hipStream_t stream) {
    (void)in_sizes; (void)n_in; (void)out_size; (void)ws_size;
    const float* inp = (const float*)d_in[0];   // [64,256,32,32]
    const float* emb = (const float*)d_in[1];   // [1024,256]
    float* out = (float*)d_out;
    char* ws = (char*)d_ws;
    int*          idx     = (int*)(ws + WS_IDX);
    unsigned int* hist    = (unsigned int*)(ws + WS_HIST);
    float*        bnorm   = (float*)(ws + WS_BNORM);
    float*        lossacc = (float*)(ws + WS_LOSS);
    float*        embT    = (float*)(ws + WS_EMBT);

    prep_kernel<<<dim3(KKE), dim3(256), 0, stream>>>(emb, embT, bnorm, hist, lossacc);
    argmin_kernel<<<dim3(8, BB), dim3(256), 0, stream>>>(inp, embT, bnorm, idx);
    onehot_kernel<<<dim3(NTOT), dim3(256), 0, stream>>>(idx, out + ENC_OFF, hist);
    out_loss_kernel<<<dim3(4096), dim3(256), 0, stream>>>(inp, embT, idx, out + OUT_OFF, lossacc);
    final_kernel<<<dim3(1), dim3(1024), 0, stream>>>(hist, lossacc, out);
}

// Round 2
// 982.664 us; speedup vs baseline: 2.8083x; 2.8083x over previous
//
#include <hip/hip_runtime.h>
#include <math.h>
#include <float.h>

// Problem constants
#define BB    64
#define CCH   256
#define KKE   1024
#define HWN   1024
#define NTOT  (BB*HWN)          // 65536
#define OUT_ELE (BB*CCH*HWN)    // 16777216
// d_out layout (floats): loss | out | perplexity | encodings
#define LOSS_OFF 0
#define OUT_OFF  1
#define PERP_OFF (1 + OUT_ELE)           // 16777217
#define ENC_OFF  (2 + OUT_ELE)           // 16777218 (byte off % 16 == 8 -> float2 stores only)

// workspace layout (bytes)
#define WS_IDX   0                        // int32[65536]   (256 KB)
#define WS_HIST  (NTOT*4)                 // uint32[1024]
#define WS_BNORM (WS_HIST + KKE*4)        // float[1024]
#define WS_LOSS  (WS_BNORM + KKE*4)       // float[1]
#define WS_ANORM 524288                   // float[65536]   (256 KB)
#define WS_EMBT  786432                   // float[256*1024] transposed emb (1 MB)
// total ws use: 1.75 MB

// ---------------- Kernel 1: transpose emb, ||e_k||^2 (fp64), zero accumulators
__global__ __launch_bounds__(256) void prep_kernel(const float* __restrict__ emb,
                                                   float* __restrict__ embT,
                                                   float* __restrict__ bnorm,
                                                   unsigned int* __restrict__ hist,
                                                   float* __restrict__ lossacc) {
    const int k = blockIdx.x;     // 0..1023
    const int t = threadIdx.x;    // 0..255 = c
    float v = emb[k*CCH + t];
    embT[(size_t)t*KKE + k] = v;
    double sq = (double)v * (double)v;
    #pragma unroll
    for (int off = 32; off; off >>= 1) sq += __shfl_down(sq, off);
    __shared__ double wred[4];
    const int wave = t >> 6, lane = t & 63;
    if (lane == 0) wred[wave] = sq;
    __syncthreads();
    if (t == 0) bnorm[k] = (float)(wred[0] + wred[1] + wred[2] + wred[3]);
    if (blockIdx.x < 4) hist[blockIdx.x*256 + t] = 0u;
    if (blockIdx.x == 4 && t == 0) *lossacc = 0.0f;
}

// ---------------- Kernel 1b: ||x_n||^2 in fp64 (separate so GEMM loop stays pure fp32)
__global__ __launch_bounds__(256) void anorm_kernel(const float* __restrict__ inp,
                                                    float* __restrict__ anorm) {
    const int b  = blockIdx.y;                       // 0..63
    const int hw = blockIdx.x * 256 + threadIdx.x;   // grid.x = 4
    const float* p = inp + (size_t)b*CCH*HWN + hw;
    double s = 0.0;
    #pragma unroll 8
    for (int c = 0; c < CCH; ++c) {
        float v = p[(size_t)c*HWN];
        s += (double)v * (double)v;
    }
    anorm[b*HWN + hw] = (float)s;
}

// ---------------- Kernel 2: fused distance GEMM + argmin
// Block: 256 threads -> 128n x 128k tile, 8x8 per thread, c-chunks of 32.
// K-loop (8 tiles of 128 codes) inside the block so argmin stays in registers.
__global__ __launch_bounds__(256, 2) void argmin_kernel(const float* __restrict__ inp,
                                                        const float* __restrict__ embT,
                                                        const float* __restrict__ bnorm,
                                                        const float* __restrict__ anorm,
                                                        int* __restrict__ idx) {
    __shared__ float As[32][128];     // A^T chunk: [cc][nn]
    __shared__ float Es[32][136];     // embT chunk: [cc][kk], padded row
    __shared__ float aS[128];         // ||x_n||^2 for the tile
    __shared__ float bS[128];         // ||e_k||^2 for current k-tile
    __shared__ float red_d[128][17];
    __shared__ int   red_k[128][17];

    const int t  = threadIdx.x;
    const int tn = t & 15;            // 0..15
    const int tk = t >> 4;            // 0..15
    const int b  = blockIdx.y;
    const int n0 = blockIdx.x * 128;
    const float* gA = inp + (size_t)b*CCH*HWN + n0;   // gA[c*1024 + nn]

    if (t < 128) aS[t] = anorm[b*HWN + n0 + t];   // first ct-barrier covers this

    float bestd[8];
    int   bestk[8];
    #pragma unroll
    for (int i = 0; i < 8; ++i) { bestd[i] = FLT_MAX; bestk[i] = 0; }

    for (int kt = 0; kt < 8; ++kt) {
        const int k0 = kt * 128;
        float acc[8][8];
        #pragma unroll
        for (int i = 0; i < 8; ++i)
            #pragma unroll
            for (int j = 0; j < 8; ++j) acc[i][j] = 0.0f;

        for (int ct = 0; ct < 8; ++ct) {
            const int c0 = ct * 32;
            __syncthreads();   // protect LDS from previous readers
            #pragma unroll
            for (int i = 0; i < 4; ++i) {          // A tile: 32x128 via float4
                int f = i*256 + t; int cc = f >> 5; int q = f & 31;
                *(float4*)&As[cc][q*4] =
                    *(const float4*)&gA[(size_t)(c0+cc)*HWN + q*4];
            }
            #pragma unroll
            for (int i = 0; i < 4; ++i) {          // E tile: 32x128 via float4
                int f = i*256 + t; int cc = f >> 5; int q = f & 31;
                *(float4*)&Es[cc][q*4] =
                    *(const float4*)&embT[(size_t)(c0+cc)*KKE + k0 + q*4];
            }
            if (ct == 0 && t < 128) bS[t] = bnorm[k0 + t];
            __syncthreads();

            #pragma unroll
            for (int cc = 0; cc < 32; ++cc) {
                float4 a0 = *(const float4*)&As[cc][tn*4];
                float4 a1 = *(const float4*)&As[cc][64 + tn*4];
                float4 e0 = *(const float4*)&Es[cc][tk*4];
                float4 e1 = *(const float4*)&Es[cc][64 + tk*4];
                float av[8] = {a0.x,a0.y,a0.z,a0.w,a1.x,a1.y,a1.z,a1.w};
                float ev[8] = {e0.x,e0.y,e0.z,e0.w,e1.x,e1.y,e1.z,e1.w};
                #pragma unroll
                for (int i = 0; i < 8; ++i)
                    #pragma unroll
                    for (int j = 0; j < 8; ++j)
                        acc[i][j] += av[i] * ev[j];
            }
        }

        // d = fp32( fp32(a + b_k) - 2*dot ), first-index tie-break via (d==, k<)
        #pragma unroll
        for (int i = 0; i < 8; ++i) {
            int nl = (i < 4) ? tn*4 + i : 64 + tn*4 + (i - 4);
            float a = aS[nl];
            #pragma unroll
            for (int j = 0; j < 8; ++j) {
                int kl = (j < 4) ? tk*4 + j : 64 + tk*4 + (j - 4);
                float s = a + bS[kl];
                float d = s - 2.0f * acc[i][j];
                int kg = k0 + kl;
                if (d < bestd[i] || (d == bestd[i] && kg < bestk[i])) {
                    bestd[i] = d; bestk[i] = kg;
                }
            }
        }
        // next kt's top-of-ct barrier protects bS/As/Es reuse
    }

    __syncthreads();
    #pragma unroll
    for (int i = 0; i < 8; ++i) {
        int nl = (i < 4) ? tn*4 + i : 64 + tn*4 + (i - 4);
        red_d[nl][tk] = bestd[i];
        red_k[nl][tk] = bestk[i];
    }
    __syncthreads();
    if (t < 128) {
        float bd = red_d[t][0]; int bk = red_k[t][0];
        #pragma unroll
        for (int g = 1; g < 16; ++g) {
            float d = red_d[t][g]; int k = red_k[t][g];
            if (d < bd || (d == bd && k < bk)) { bd = d; bk = k; }
        }
        idx[b*HWN + n0 + t] = bk;
    }
}

// ---------------- Kernel 3: encodings one-hot (zero + scatter fused) + histogram
__global__ __launch_bounds__(256) void onehot_kernel(const int* __restrict__ idx,
                                                     float* __restrict__ enc,
                                                     unsigned int* __restrict__ hist) {
    const int n = blockIdx.x;
    const int t = threadIdx.x;
    const int k = idx[n];                 // broadcast read
    const int j4 = t * 4;
    float2 v0 = {0.0f, 0.0f}, v1 = {0.0f, 0.0f};
    if (k == j4)     v0.x = 1.0f;
    if (k == j4 + 1) v0.y = 1.0f;
    if (k == j4 + 2) v1.x = 1.0f;
    if (k == j4 + 3) v1.y = 1.0f;
    float* row = enc + (size_t)n * KKE;
    *(float2*)&row[j4]     = v0;          // base % 16 == 8 -> float2 alignment only
    *(float2*)&row[j4 + 2] = v1;
    if (t == 0) atomicAdd(&hist[k], 1u);
}

// ---------------- Kernel 4: out = gather(e) (value of STE) + loss partial sums
__global__ __launch_bounds__(256) void out_loss_kernel(const float* __restrict__ inp,
                                                       const float* __restrict__ embT,
                                                       const int* __restrict__ idx,
                                                       float* __restrict__ out,
                                                       float* __restrict__ lossacc) {
    const int t = threadIdx.x;
    const size_t stride = (size_t)gridDim.x * 256;
    float lsum = 0.0f;
    for (size_t m = (size_t)blockIdx.x * 256 + t; m < (size_t)OUT_ELE; m += stride) {
        int hw = (int)(m & 1023);
        int c  = (int)((m >> 10) & 255);
        int b  = (int)(m >> 18);
        int k  = idx[b*HWN + hw];
        float e = embT[(size_t)c*KKE + k];  // same-row gather: L1/L2 friendly
        float x = inp[m];
        out[m] = e;
        float df = e - x;
        lsum += df * df;
    }
    #pragma unroll
    for (int off = 32; off; off >>= 1) lsum += __shfl_down(lsum, off);
    __shared__ float wred[4];
    const int wave = t >> 6, lane = t & 63;
    if (lane == 0) wred[wave] = lsum;
    __syncthreads();
    if (t == 0) atomicAdd(lossacc, wred[0] + wred[1] + wred[2] + wred[3]);
}

// ---------------- Kernel 5: finalize loss + perplexity
__global__ __launch_bounds__(1024) void final_kernel(const unsigned int* __restrict__ hist,
                                                     const float* __restrict__ lossacc,
                                                     float* __restrict__ d_out) {
    const int t = threadIdx.x;   // 0..1023 = k
    float p = (float)hist[t] * (1.0f / 65536.0f);
    float v = p * logf(p + 1e-10f);
    #pragma unroll
    for (int off = 32; off; off >>= 1) v += __shfl_down(v, off);
    __shared__ float wred[16];
    const int wave = t >> 6, lane = t & 63;
    if (lane == 0) wred[wave] = v;
    __syncthreads();
    if (t == 0) {
        float s = 0.0f;
        #pragma unroll
        for (int i = 0; i < 16; ++i) s += wred[i];
        d_out[PERP_OFF] = expf(-s);
        d_out[LOSS_OFF] = 1.25f * (*lossacc) * (1.0f / (float)OUT_ELE);
    }
}

extern "C" void kernel_launch(void* const* d_in, const int* in_sizes, int n_in,
                              void* d_out, int out_size, void* d_ws, size_t ws_size,
                              hipStream_t stream) {
    (void)in_sizes; (void)n_in; (void)out_size; (void)ws_size;
    const float* inp = (const float*)d_in[0];   // [64,256,32,32]
    const float* emb = (const float*)d_in[1];   // [1024,256]
    float* out = (float*)d_out;
    char* ws = (char*)d_ws;
    int*          idx     = (int*)(ws + WS_IDX);
    unsigned int* hist    = (unsigned int*)(ws + WS_HIST);
    float*        bnorm   = (float*)(ws + WS_BNORM);
    float*        lossacc = (float*)(ws + WS_LOSS);
    float*        anorm   = (float*)(ws + WS_ANORM);
    float*        embT    = (float*)(ws + WS_EMBT);

    prep_kernel<<<dim3(KKE), dim3(256), 0, stream>>>(emb, embT, bnorm, hist, lossacc);
    anorm_kernel<<<dim3(4, BB), dim3(256), 0, stream>>>(inp, anorm);
    argmin_kernel<<<dim3(8, BB), dim3(256), 0, stream>>>(inp, embT, bnorm, anorm, idx);
    onehot_kernel<<<dim3(NTOT), dim3(256), 0, stream>>>(idx, out + ENC_OFF, hist);
    out_loss_kernel<<<dim3(4096), dim3(256), 0, stream>>>(inp, embT, idx, out + OUT_OFF, lossacc);
    final_kernel<<<dim3(1), dim3(1024), 0, stream>>>(hist, lossacc, out);
}

// Round 3
// 909.625 us; speedup vs baseline: 3.0338x; 1.0803x over previous
//
#include <hip/hip_runtime.h>
#include <hip/hip_bf16.h>
#include <math.h>
#include <float.h>

#define BB    64
#define CCH   256
#define KKE   1024
#define HWN   1024
#define NTOT  (BB*HWN)          // 65536
#define OUT_ELE (BB*CCH*HWN)    // 16777216
#define LOSS_OFF 0
#define OUT_OFF  1
#define PERP_OFF (1 + OUT_ELE)
#define ENC_OFF  (2 + OUT_ELE)   // byte off % 16 == 8 -> float2 stores only

// workspace layout (bytes)
#define WS_IDX    0               // int[65536]
#define WS_ANORM  262144          // float[65536]
#define WS_HIST   524288          // uint[1024]
#define WS_BNORM  528384          // float[1024]
#define WS_MISC   532480          // [0]=lossacc (float), [1]=counter (int)
#define WS_LIST   536576          // int[65536]
#define WS_EMBT   798720          // float[256*1024]
#define WS_EHI    1847296         // bf16[8][1024][32] chunked
#define WS_ELO    2371584
#define WS_CD1    2895872         // float[8][65536]
#define WS_CK1    4993024         // int[8][65536]
#define WS_CD2    7090176         // float[8][65536]
// end ~9.2 MB

typedef __attribute__((ext_vector_type(4))) float f32x4;
typedef __attribute__((ext_vector_type(8))) short s16x8;

#define TAU 2e-4f

// merge two (d1,k1,d2) candidate sets; first-index tie-break
__device__ inline void merge_cand(float& d1, int& k1, float& d2,
                                  float od1, int ok1, float od2) {
    bool w = (od1 < d1) || (od1 == d1 && ok1 < k1);
    float loser_d1 = w ? d1 : od1;
    float winner_d2 = w ? od2 : d2;
    d2 = fminf(winner_d2, loser_d1);
    if (w) { d1 = od1; k1 = ok1; }
}

// ---------------- Kernel 1: transpose emb, ||e||^2 fp64, bf16 split of emb, zero accums
__global__ __launch_bounds__(256) void prep_kernel(const float* __restrict__ emb,
                                                   float* __restrict__ embT,
                                                   float* __restrict__ bnorm,
                                                   short* __restrict__ ehi,
                                                   short* __restrict__ elo,
                                                   unsigned int* __restrict__ hist,
                                                   float* __restrict__ misc) {
    const int k = blockIdx.x;     // 0..1023
    const int t = threadIdx.x;    // 0..255 = c
    float v = emb[k*CCH + t];
    embT[(size_t)t*KKE + k] = v;
    // bf16 split (RNE): v = hi + lo + eps(2^-18)
    __hip_bfloat16 h = __float2bfloat16(v);
    float hf = __bfloat162float(h);
    __hip_bfloat16 l = __float2bfloat16(v - hf);
    size_t eoff = (size_t)(t >> 5)*32768 + (size_t)k*32 + (t & 31);
    ehi[eoff] = *(short*)&h;
    elo[eoff] = *(short*)&l;
    double sq = (double)v * (double)v;
    #pragma unroll
    for (int off = 32; off; off >>= 1) sq += __shfl_down(sq, off);
    __shared__ double wred[4];
    const int wave = t >> 6, lane = t & 63;
    if (lane == 0) wred[wave] = sq;
    __syncthreads();
    if (t == 0) bnorm[k] = (float)(wred[0] + wred[1] + wred[2] + wred[3]);
    if (blockIdx.x < 4) hist[blockIdx.x*256 + t] = 0u;
    if (blockIdx.x == 4 && t == 0) { misc[0] = 0.0f; ((int*)misc)[1] = 0; }
}

// ---------------- Kernel 1b: ||x_n||^2 fp64
__global__ __launch_bounds__(256) void anorm_kernel(const float* __restrict__ inp,
                                                    float* __restrict__ anorm) {
    const int b  = blockIdx.y;
    const int hw = blockIdx.x * 256 + threadIdx.x;
    const float* p = inp + (size_t)b*CCH*HWN + hw;
    double s = 0.0;
    #pragma unroll 8
    for (int c = 0; c < CCH; ++c) {
        float v = p[(size_t)c*HWN];
        s += (double)v * (double)v;
    }
    anorm[b*HWN + hw] = (float)s;
}

// ---------------- Kernel 2: MFMA distance + per-k-block argmin candidates
// grid (512 n-tiles, 8 k-tiles), 256 thr = 4 waves. Block tile 128n x 128k.
// Wave tile 32n x 128k: 2 rowgroups x 8 coltiles of 16x16x32 bf16 MFMA.
__global__ __launch_bounds__(256, 3) void argmin_mfma(const float* __restrict__ inp,
                                                      const short* __restrict__ ehi,
                                                      const short* __restrict__ elo,
                                                      const float* __restrict__ anorm,
                                                      const float* __restrict__ bnorm,
                                                      float* __restrict__ cd1,
                                                      int* __restrict__ ck1,
                                                      float* __restrict__ cd2) {
    __shared__ short Ahi[128*40];   // rows padded to 40 shorts (80 B)
    __shared__ short Alo[128*40];
    __shared__ short Bhi[128*32];   // [code][c] contiguous
    __shared__ short Blo[128*32];

    const int t    = threadIdx.x;
    const int w    = t >> 6;
    const int lane = t & 63;
    const int q    = lane >> 4;      // quad 0..3
    const int l15  = lane & 15;
    const int n0   = blockIdx.x * 128;
    const int k0   = blockIdx.y * 128;
    const int b    = n0 >> 10;
    const int hw0  = n0 & 1023;
    const float* gA = inp + (size_t)b*CCH*HWN + hw0;

    const int na = t & 127;          // A staging: row
    const int ch = t >> 7;           // A staging: c-half (16 c each)

    f32x4 acc[2][8];
    #pragma unroll
    for (int i = 0; i < 2; ++i)
        #pragma unroll
        for (int j = 0; j < 8; ++j) acc[i][j] = (f32x4){0.f,0.f,0.f,0.f};

    for (int chunk = 0; chunk < 8; ++chunk) {
        const int c0 = chunk * 32;
        __syncthreads();
        // ---- A: read 16 fp32 (coalesced over na), split, write 2x b128 each
        float v[16];
        #pragma unroll
        for (int cc = 0; cc < 16; ++cc)
            v[cc] = gA[(size_t)(c0 + ch*16 + cc) * HWN + na];
        short hs[16], ls[16];
        #pragma unroll
        for (int cc = 0; cc < 16; ++cc) {
            __hip_bfloat16 h = __float2bfloat16(v[cc]);
            float hf = __bfloat162float(h);
            __hip_bfloat16 l = __float2bfloat16(v[cc] - hf);
            hs[cc] = *(short*)&h; ls[cc] = *(short*)&l;
        }
        *(s16x8*)&Ahi[na*40 + ch*16]     = *(s16x8*)&hs[0];
        *(s16x8*)&Ahi[na*40 + ch*16 + 8] = *(s16x8*)&hs[8];
        *(s16x8*)&Alo[na*40 + ch*16]     = *(s16x8*)&ls[0];
        *(s16x8*)&Alo[na*40 + ch*16 + 8] = *(s16x8*)&ls[8];
        // ---- B: copy pre-split chunked tile (fully coalesced, conflict-free)
        {
            const size_t ebase = (size_t)chunk*32768 + (size_t)k0*32;
            *(s16x8*)&Bhi[t*8]        = *(const s16x8*)&ehi[ebase + t*8];
            *(s16x8*)&Bhi[2048 + t*8] = *(const s16x8*)&ehi[ebase + 2048 + t*8];
            *(s16x8*)&Blo[t*8]        = *(const s16x8*)&elo[ebase + t*8];
            *(s16x8*)&Blo[2048 + t*8] = *(const s16x8*)&elo[ebase + 2048 + t*8];
        }
        __syncthreads();
        // ---- compute: A frags once, loop 8 col-tiles
        s16x8 afh0 = *(s16x8*)&Ahi[(w*32 +      l15)*40 + q*8];
        s16x8 afh1 = *(s16x8*)&Ahi[(w*32 + 16 + l15)*40 + q*8];
        s16x8 afl0 = *(s16x8*)&Alo[(w*32 +      l15)*40 + q*8];
        s16x8 afl1 = *(s16x8*)&Alo[(w*32 + 16 + l15)*40 + q*8];
        #pragma unroll
        for (int ct = 0; ct < 8; ++ct) {
            s16x8 bh = *(s16x8*)&Bhi[(ct*16 + l15)*32 + q*8];
            s16x8 bl = *(s16x8*)&Blo[(ct*16 + l15)*32 + q*8];
            acc[0][ct] = __builtin_amdgcn_mfma_f32_16x16x32_bf16(afh0, bh, acc[0][ct], 0, 0, 0);
            acc[0][ct] = __builtin_amdgcn_mfma_f32_16x16x32_bf16(afh0, bl, acc[0][ct], 0, 0, 0);
            acc[0][ct] = __builtin_amdgcn_mfma_f32_16x16x32_bf16(afl0, bh, acc[0][ct], 0, 0, 0);
            acc[1][ct] = __builtin_amdgcn_mfma_f32_16x16x32_bf16(afh1, bh, acc[1][ct], 0, 0, 0);
            acc[1][ct] = __builtin_amdgcn_mfma_f32_16x16x32_bf16(afh1, bl, acc[1][ct], 0, 0, 0);
            acc[1][ct] = __builtin_amdgcn_mfma_f32_16x16x32_bf16(afl1, bh, acc[1][ct], 0, 0, 0);
        }
    }

    // ---- epilogue: d = (anorm+bnorm) - 2*dot; per-row best/second-best over 128 k
    float bnv[8];
    #pragma unroll
    for (int ct = 0; ct < 8; ++ct) bnv[ct] = bnorm[k0 + ct*16 + l15];

    #pragma unroll
    for (int rg = 0; rg < 2; ++rg) {
        #pragma unroll
        for (int reg = 0; reg < 4; ++reg) {
            const int n = n0 + w*32 + rg*16 + q*4 + reg;   // C/D: row = quad*4+reg
            const float a = anorm[n];
            float d1 = FLT_MAX, d2 = FLT_MAX; int k1 = 0;
            #pragma unroll
            for (int ct = 0; ct < 8; ++ct) {
                float s = a + bnv[ct];
                float d = s - 2.0f * acc[rg][ct][reg];
                int   k = k0 + ct*16 + l15;                // C/D: col = lane&15
                if (d < d1 || (d == d1 && k < k1)) { d2 = d1; d1 = d; k1 = k; }
                else d2 = fminf(d2, d);
            }
            #pragma unroll
            for (int off = 1; off < 16; off <<= 1) {
                float od1 = __shfl_xor(d1, off);
                int   ok1 = __shfl_xor(k1, off);
                float od2 = __shfl_xor(d2, off);
                merge_cand(d1, k1, d2, od1, ok1, od2);
            }
            if (l15 == 0) {
                const size_t o = (size_t)blockIdx.y*NTOT + n;
                cd1[o] = d1; ck1[o] = k1; cd2[o] = d2;
            }
        }
    }
}

// ---------------- Kernel 3: merge 8 k-block candidates, flag near-ties
__global__ __launch_bounds__(256) void reduce_kernel(const float* __restrict__ cd1,
                                                     const int* __restrict__ ck1,
                                                     const float* __restrict__ cd2,
                                                     int* __restrict__ idx,
                                                     int* __restrict__ list,
                                                     int* __restrict__ counter) {
    const int n = blockIdx.x*256 + threadIdx.x;
    float d1 = cd1[n]; int k1 = ck1[n]; float d2 = cd2[n];
    #pragma unroll
    for (int kb = 1; kb < 8; ++kb) {
        const size_t o = (size_t)kb*NTOT + n;
        merge_cand(d1, k1, d2, cd1[o], ck1[o], cd2[o]);
    }
    idx[n] = k1;
    if (d2 - d1 < TAU) {
        int p = atomicAdd(counter, 1);
        list[p] = n;
    }
}

// ---------------- Kernel 4: exact fp32 rescore of flagged vectors (reference semantics)
__global__ __launch_bounds__(256) void rescore_kernel(const float* __restrict__ inp,
                                                      const float* __restrict__ emb,
                                                      const float* __restrict__ anorm,
                                                      const float* __restrict__ bnorm,
                                                      const int* __restrict__ list,
                                                      const int* __restrict__ counter,
                                                      int* __restrict__ idx) {
    __shared__ float xs[256];
    __shared__ float rd[256];
    __shared__ int   rk[256];
    const int t = threadIdx.x;
    const int cnt = *counter;
    for (int f = blockIdx.x; f < cnt; f += gridDim.x) {
        const int n = list[f];
        const int b = n >> 10, hw = n & 1023;
        __syncthreads();
        xs[t] = inp[(size_t)b*CCH*HWN + (size_t)t*HWN + hw];
        __syncthreads();
        const float a = anorm[n];
        float bd = FLT_MAX; int bk = 0;
        for (int kk = 0; kk < 4; ++kk) {
            const int k = kk*256 + t;
            const float* er = emb + (size_t)k*CCH;
            float dot = 0.0f;
            for (int c = 0; c < CCH; ++c) dot += xs[c] * er[c];   // sequential fp32
            float s = a + bnorm[k];
            float d = s - 2.0f * dot;
            if (d < bd || (d == bd && k < bk)) { bd = d; bk = k; }
        }
        rd[t] = bd; rk[t] = bk;
        __syncthreads();
        for (int stride = 128; stride; stride >>= 1) {
            if (t < stride) {
                float od = rd[t+stride]; int ok = rk[t+stride];
                if (od < rd[t] || (od == rd[t] && ok < rk[t])) { rd[t] = od; rk[t] = ok; }
            }
            __syncthreads();
        }
        if (t == 0) idx[n] = rk[0];
    }
}

// ---------------- Kernel 5: encodings one-hot + histogram (16 rows/block)
__global__ __launch_bounds__(256) void onehot_kernel(const int* __restrict__ idx,
                                                     float* __restrict__ enc,
                                                     unsigned int* __restrict__ hist) {
    const int t = threadIdx.x;
    const int j4 = t * 4;
    for (int r = 0; r < 16; ++r) {
        const int n = blockIdx.x*16 + r;
        const int k = idx[n];
        float2 v0 = {0.0f, 0.0f}, v1 = {0.0f, 0.0f};
        if (k == j4)     v0.x = 1.0f;
        if (k == j4 + 1) v0.y = 1.0f;
        if (k == j4 + 2) v1.x = 1.0f;
        if (k == j4 + 3) v1.y = 1.0f;
        float* row = enc + (size_t)n * KKE;
        *(float2*)&row[j4]     = v0;
        *(float2*)&row[j4 + 2] = v1;
        if (t == 0) atomicAdd(&hist[k], 1u);
    }
}

// ---------------- Kernel 6: out = gather(e), loss partials
__global__ __launch_bounds__(256) void out_loss_kernel(const float* __restrict__ inp,
                                                       const float* __restrict__ embT,
                                                       const int* __restrict__ idx,
                                                       float* __restrict__ out,
                                                       float* __restrict__ lossacc) {
    const int t = threadIdx.x;
    const size_t stride = (size_t)gridDim.x * 256;
    float lsum = 0.0f;
    for (size_t m = (size_t)blockIdx.x * 256 + t; m < (size_t)OUT_ELE; m += stride) {
        int hw = (int)(m & 1023);
        int c  = (int)((m >> 10) & 255);
        int b  = (int)(m >> 18);
        int k  = idx[b*HWN + hw];
        float e = embT[(size_t)c*KKE + k];
        float x = inp[m];
        out[m] = e;
        float df = e - x;
        lsum += df * df;
    }
    #pragma unroll
    for (int off = 32; off; off >>= 1) lsum += __shfl_down(lsum, off);
    __shared__ float wred[4];
    const int wave = t >> 6, lane = t & 63;
    if (lane == 0) wred[wave] = lsum;
    __syncthreads();
    if (t == 0) atomicAdd(lossacc, wred[0] + wred[1] + wred[2] + wred[3]);
}

// ---------------- Kernel 7: finalize
__global__ __launch_bounds__(1024) void final_kernel(const unsigned int* __restrict__ hist,
                                                     const float* __restrict__ lossacc,
                                                     float* __restrict__ d_out) {
    const int t = threadIdx.x;
    float p = (float)hist[t] * (1.0f / 65536.0f);
    float v = p * logf(p + 1e-10f);
    #pragma unroll
    for (int off = 32; off; off >>= 1) v += __shfl_down(v, off);
    __shared__ float wred[16];
    const int wave = t >> 6, lane = t & 63;
    if (lane == 0) wred[wave] = v;
    __syncthreads();
    if (t == 0) {
        float s = 0.0f;
        #pragma unroll
        for (int i = 0; i < 16; ++i) s += wred[i];
        d_out[PERP_OFF] = expf(-s);
        d_out[LOSS_OFF] = 1.25f * (*lossacc) * (1.0f / (float)OUT_ELE);
    }
}

extern "C" void kernel_launch(void* const* d_in, const int* in_sizes, int n_in,
                              void* d_out, int out_size, void* d_ws, size_t ws_size,
                              hipStream_t stream) {
    (void)in_sizes; (void)n_in; (void)out_size; (void)ws_size;
    const float* inp = (const float*)d_in[0];
    const float* emb = (const float*)d_in[1];
    float* out = (float*)d_out;
    char* ws = (char*)d_ws;
    int*          idx     = (int*)(ws + WS_IDX);
    float*        anorm   = (float*)(ws + WS_ANORM);
    unsigned int* hist    = (unsigned int*)(ws + WS_HIST);
    float*        bnorm   = (float*)(ws + WS_BNORM);
    float*        misc    = (float*)(ws + WS_MISC);
    int*          list    = (int*)(ws + WS_LIST);
    float*        embT    = (float*)(ws + WS_EMBT);
    short*        ehi     = (short*)(ws + WS_EHI);
    short*        elo     = (short*)(ws + WS_ELO);
    float*        cd1     = (float*)(ws + WS_CD1);
    int*          ck1     = (int*)(ws + WS_CK1);
    float*        cd2     = (float*)(ws + WS_CD2);
    int*          counter = ((int*)misc) + 1;

    prep_kernel<<<dim3(KKE), dim3(256), 0, stream>>>(emb, embT, bnorm, ehi, elo, hist, misc);
    anorm_kernel<<<dim3(4, BB), dim3(256), 0, stream>>>(inp, anorm);
    argmin_mfma<<<dim3(512, 8), dim3(256), 0, stream>>>(inp, ehi, elo, anorm, bnorm, cd1, ck1, cd2);
    reduce_kernel<<<dim3(256), dim3(256), 0, stream>>>(cd1, ck1, cd2, idx, list, counter);
    rescore_kernel<<<dim3(512), dim3(256), 0, stream>>>(inp, emb, anorm, bnorm, list, counter, idx);
    onehot_kernel<<<dim3(4096), dim3(256), 0, stream>>>(idx, out + ENC_OFF, hist);
    out_loss_kernel<<<dim3(4096), dim3(256), 0, stream>>>(inp, embT, idx, out + OUT_OFF, misc);
    final_kernel<<<dim3(1), dim3(1024), 0, stream>>>(hist, misc, out);
}

// Round 4
// 745.177 us; speedup vs baseline: 3.7033x; 1.2207x over previous
//
#include <hip/hip_runtime.h>
#include <hip/hip_bf16.h>
#include <math.h>
#include <float.h>

#define BB    64
#define CCH   256
#define KKE   1024
#define HWN   1024
#define NTOT  (BB*HWN)          // 65536
#define OUT_ELE (BB*CCH*HWN)    // 16777216
#define LOSS_OFF 0
#define OUT_OFF  1
#define PERP_OFF (1 + OUT_ELE)
#define ENC_OFF  (2 + OUT_ELE)   // byte off % 16 == 8 -> float2 stores only

// workspace layout (bytes)
#define WS_IDX    0               // int[65536]
#define WS_ANORM  262144          // float[65536]
#define WS_HIST   524288          // uint[1024]
#define WS_BNORM  528384          // float[1024]
#define WS_MISC   532480          // [0]=lossacc (float), [1]=counter (int)
#define WS_LIST   536576          // int[65536]
#define WS_EMBT   798720          // float[256*1024]
#define WS_EHI    1847296         // bf16[8][1024][32] chunked
#define WS_ELO    2371584
#define WS_CD1    2895872         // float[8][65536]
#define WS_CK1    4993024         // int[8][65536]
#define WS_CD2    7090176         // float[8][65536]
// end ~9.2 MB

typedef __attribute__((ext_vector_type(4))) float f32x4;
typedef __attribute__((ext_vector_type(8))) short s16x8;

#define TAU 2e-4f

// merge two (d1,k1,d2) candidate sets; first-index tie-break
__device__ inline void merge_cand(float& d1, int& k1, float& d2,
                                  float od1, int ok1, float od2) {
    bool w = (od1 < d1) || (od1 == d1 && ok1 < k1);
    float loser_d1 = w ? d1 : od1;
    float winner_d2 = w ? od2 : d2;
    d2 = fminf(winner_d2, loser_d1);
    if (w) { d1 = od1; k1 = ok1; }
}

// ---------------- Kernel 1: transpose emb, ||e||^2 fp64, bf16 split of emb, zero accums
__global__ __launch_bounds__(256) void prep_kernel(const float* __restrict__ emb,
                                                   float* __restrict__ embT,
                                                   float* __restrict__ bnorm,
                                                   short* __restrict__ ehi,
                                                   short* __restrict__ elo,
                                                   unsigned int* __restrict__ hist,
                                                   float* __restrict__ misc) {
    const int k = blockIdx.x;     // 0..1023
    const int t = threadIdx.x;    // 0..255 = c
    float v = emb[k*CCH + t];
    embT[(size_t)t*KKE + k] = v;
    // bf16 split (RNE): v = hi + lo + eps(~2^-17 |v|)
    __hip_bfloat16 h = __float2bfloat16(v);
    float hf = __bfloat162float(h);
    __hip_bfloat16 l = __float2bfloat16(v - hf);
    size_t eoff = (size_t)(t >> 5)*32768 + (size_t)k*32 + (t & 31);
    ehi[eoff] = *(short*)&h;
    elo[eoff] = *(short*)&l;
    double sq = (double)v * (double)v;
    #pragma unroll
    for (int off = 32; off; off >>= 1) sq += __shfl_down(sq, off);
    __shared__ double wred[4];
    const int wave = t >> 6, lane = t & 63;
    if (lane == 0) wred[wave] = sq;
    __syncthreads();
    if (t == 0) bnorm[k] = (float)(wred[0] + wred[1] + wred[2] + wred[3]);
    if (blockIdx.x < 4) hist[blockIdx.x*256 + t] = 0u;
    if (blockIdx.x == 4 && t == 0) { misc[0] = 0.0f; ((int*)misc)[1] = 0; }
}

// ---------------- Kernel 1b: ||x_n||^2 fp64
__global__ __launch_bounds__(256) void anorm_kernel(const float* __restrict__ inp,
                                                    float* __restrict__ anorm) {
    const int b  = blockIdx.y;
    const int hw = blockIdx.x * 256 + threadIdx.x;
    const float* p = inp + (size_t)b*CCH*HWN + hw;
    double s = 0.0;
    #pragma unroll 8
    for (int c = 0; c < CCH; ++c) {
        float v = p[(size_t)c*HWN];
        s += (double)v * (double)v;
    }
    anorm[b*HWN + hw] = (float)s;
}

// ---------------- Kernel 2: MFMA distance + per-k-block argmin candidates
// grid (512 n-tiles, 8 k-tiles), 256 thr = 4 waves. Block tile 128n x 128k.
__global__ __launch_bounds__(256, 3) void argmin_mfma(const float* __restrict__ inp,
                                                      const short* __restrict__ ehi,
                                                      const short* __restrict__ elo,
                                                      const float* __restrict__ anorm,
                                                      const float* __restrict__ bnorm,
                                                      float* __restrict__ cd1,
                                                      int* __restrict__ ck1,
                                                      float* __restrict__ cd2) {
    __shared__ short Ahi[128*40];   // rows padded to 40 shorts (80 B): 2-way = free
    __shared__ short Alo[128*40];
    __shared__ short Bhi[128*40];   // [code][c], padded like A
    __shared__ short Blo[128*40];

    const int t    = threadIdx.x;
    const int w    = t >> 6;
    const int lane = t & 63;
    const int q    = lane >> 4;      // quad 0..3
    const int l15  = lane & 15;
    const int n0   = blockIdx.x * 128;
    const int k0   = blockIdx.y * 128;
    const int b    = n0 >> 10;
    const int hw0  = n0 & 1023;
    const float* gA = inp + (size_t)b*CCH*HWN + hw0;

    const int na = t & 127;          // A staging: row
    const int ch = t >> 7;           // A staging: c-half (16 c each)
    const int br = t >> 2;           // B staging: code row 0..63
    const int bc = (t & 3) * 8;      // B staging: c offset

    f32x4 acc[2][8];
    #pragma unroll
    for (int i = 0; i < 2; ++i)
        #pragma unroll
        for (int j = 0; j < 8; ++j) acc[i][j] = (f32x4){0.f,0.f,0.f,0.f};

    for (int chunk = 0; chunk < 8; ++chunk) {
        const int c0 = chunk * 32;
        __syncthreads();
        // ---- A: read 16 fp32 (coalesced over na), split, write 2x b128 each
        float v[16];
        #pragma unroll
        for (int cc = 0; cc < 16; ++cc)
            v[cc] = gA[(size_t)(c0 + ch*16 + cc) * HWN + na];
        short hs[16], ls[16];
        #pragma unroll
        for (int cc = 0; cc < 16; ++cc) {
            __hip_bfloat16 h = __float2bfloat16(v[cc]);
            float hf = __bfloat162float(h);
            __hip_bfloat16 l = __float2bfloat16(v[cc] - hf);
            hs[cc] = *(short*)&h; ls[cc] = *(short*)&l;
        }
        *(s16x8*)&Ahi[na*40 + ch*16]     = *(s16x8*)&hs[0];
        *(s16x8*)&Ahi[na*40 + ch*16 + 8] = *(s16x8*)&hs[8];
        *(s16x8*)&Alo[na*40 + ch*16]     = *(s16x8*)&ls[0];
        *(s16x8*)&Alo[na*40 + ch*16 + 8] = *(s16x8*)&ls[8];
        // ---- B: copy pre-split chunked tile (coalesced src, padded dst)
        {
            const size_t ebase = (size_t)chunk*32768 + (size_t)k0*32;
            *(s16x8*)&Bhi[br*40 + bc]        = *(const s16x8*)&ehi[ebase + t*8];
            *(s16x8*)&Bhi[(64+br)*40 + bc]   = *(const s16x8*)&ehi[ebase + 2048 + t*8];
            *(s16x8*)&Blo[br*40 + bc]        = *(const s16x8*)&elo[ebase + t*8];
            *(s16x8*)&Blo[(64+br)*40 + bc]   = *(const s16x8*)&elo[ebase + 2048 + t*8];
        }
        __syncthreads();
        // ---- compute: A frags once, loop 8 col-tiles
        s16x8 afh0 = *(s16x8*)&Ahi[(w*32 +      l15)*40 + q*8];
        s16x8 afh1 = *(s16x8*)&Ahi[(w*32 + 16 + l15)*40 + q*8];
        s16x8 afl0 = *(s16x8*)&Alo[(w*32 +      l15)*40 + q*8];
        s16x8 afl1 = *(s16x8*)&Alo[(w*32 + 16 + l15)*40 + q*8];
        #pragma unroll
        for (int ct = 0; ct < 8; ++ct) {
            s16x8 bh = *(s16x8*)&Bhi[(ct*16 + l15)*40 + q*8];
            s16x8 bl = *(s16x8*)&Blo[(ct*16 + l15)*40 + q*8];
            acc[0][ct] = __builtin_amdgcn_mfma_f32_16x16x32_bf16(afh0, bh, acc[0][ct], 0, 0, 0);
            acc[0][ct] = __builtin_amdgcn_mfma_f32_16x16x32_bf16(afh0, bl, acc[0][ct], 0, 0, 0);
            acc[0][ct] = __builtin_amdgcn_mfma_f32_16x16x32_bf16(afl0, bh, acc[0][ct], 0, 0, 0);
            acc[1][ct] = __builtin_amdgcn_mfma_f32_16x16x32_bf16(afh1, bh, acc[1][ct], 0, 0, 0);
            acc[1][ct] = __builtin_amdgcn_mfma_f32_16x16x32_bf16(afh1, bl, acc[1][ct], 0, 0, 0);
            acc[1][ct] = __builtin_amdgcn_mfma_f32_16x16x32_bf16(afl1, bh, acc[1][ct], 0, 0, 0);
        }
    }

    // ---- epilogue: d = (anorm+bnorm) - 2*dot; per-row best/second-best over 128 k
    float bnv[8];
    #pragma unroll
    for (int ct = 0; ct < 8; ++ct) bnv[ct] = bnorm[k0 + ct*16 + l15];

    #pragma unroll
    for (int rg = 0; rg < 2; ++rg) {
        #pragma unroll
        for (int reg = 0; reg < 4; ++reg) {
            const int n = n0 + w*32 + rg*16 + q*4 + reg;   // C/D: row = quad*4+reg
            const float a = anorm[n];
            float d1 = FLT_MAX, d2 = FLT_MAX; int k1 = 0;
            #pragma unroll
            for (int ct = 0; ct < 8; ++ct) {
                float s = a + bnv[ct];
                float d = s - 2.0f * acc[rg][ct][reg];
                int   k = k0 + ct*16 + l15;                // C/D: col = lane&15
                if (d < d1 || (d == d1 && k < k1)) { d2 = d1; d1 = d; k1 = k; }
                else d2 = fminf(d2, d);
            }
            #pragma unroll
            for (int off = 1; off < 16; off <<= 1) {
                float od1 = __shfl_xor(d1, off);
                int   ok1 = __shfl_xor(k1, off);
                float od2 = __shfl_xor(d2, off);
                merge_cand(d1, k1, d2, od1, ok1, od2);
            }
            if (l15 == 0) {
                const size_t o = (size_t)blockIdx.y*NTOT + n;
                cd1[o] = d1; ck1[o] = k1; cd2[o] = d2;
            }
        }
    }
}

// ---------------- Kernel 3: merge 8 k-block candidates, flag near-ties
__global__ __launch_bounds__(256) void reduce_kernel(const float* __restrict__ cd1,
                                                     const int* __restrict__ ck1,
                                                     const float* __restrict__ cd2,
                                                     int* __restrict__ idx,
                                                     int* __restrict__ list,
                                                     int* __restrict__ counter) {
    const int n = blockIdx.x*256 + threadIdx.x;
    float d1 = cd1[n]; int k1 = ck1[n]; float d2 = cd2[n];
    #pragma unroll
    for (int kb = 1; kb < 8; ++kb) {
        const size_t o = (size_t)kb*NTOT + n;
        merge_cand(d1, k1, d2, cd1[o], ck1[o], cd2[o]);
    }
    idx[n] = k1;
    if (d2 - d1 < TAU) {
        int p = atomicAdd(counter, 1);
        list[p] = n;
    }
}

// ---------------- Kernel 4: exact fp32 rescore (reference sequential-c semantics),
// coalesced via embT: at fixed c, thread t reads embT[c*1024 + kk*256 + t].
__global__ __launch_bounds__(256) void rescore_kernel(const float* __restrict__ inp,
                                                      const float* __restrict__ embT,
                                                      const float* __restrict__ anorm,
                                                      const float* __restrict__ bnorm,
                                                      const int* __restrict__ list,
                                                      const int* __restrict__ counter,
                                                      int* __restrict__ idx) {
    __shared__ float xs[256];
    __shared__ float rd[256];
    __shared__ int   rk[256];
    const int t = threadIdx.x;
    const int cnt = *counter;
    for (int f = blockIdx.x; f < cnt; f += gridDim.x) {
        const int n = list[f];
        const int b = n >> 10, hw = n & 1023;
        __syncthreads();
        xs[t] = inp[(size_t)b*CCH*HWN + (size_t)t*HWN + hw];
        __syncthreads();
        float dot0 = 0.f, dot1 = 0.f, dot2 = 0.f, dot3 = 0.f;
        #pragma unroll 4
        for (int c = 0; c < CCH; ++c) {
            const float xc = xs[c];
            const float* row = embT + (size_t)c*KKE + t;
            dot0 += xc * row[0];
            dot1 += xc * row[256];
            dot2 += xc * row[512];
            dot3 += xc * row[768];
        }
        const float a = anorm[n];
        float bd = FLT_MAX; int bk = 0;
        float dots[4] = {dot0, dot1, dot2, dot3};
        #pragma unroll
        for (int kk = 0; kk < 4; ++kk) {
            const int k = kk*256 + t;
            float s = a + bnorm[k];
            float d = s - 2.0f * dots[kk];
            if (d < bd || (d == bd && k < bk)) { bd = d; bk = k; }
        }
        rd[t] = bd; rk[t] = bk;
        __syncthreads();
        for (int stride = 128; stride; stride >>= 1) {
            if (t < stride) {
                float od = rd[t+stride]; int ok = rk[t+stride];
                if (od < rd[t] || (od == rd[t] && ok < rk[t])) { rd[t] = od; rk[t] = ok; }
            }
            __syncthreads();
        }
        if (t == 0) idx[n] = rk[0];
    }
}

// ---------------- Kernel 5: encodings one-hot + histogram (16 rows/block)
__global__ __launch_bounds__(256) void onehot_kernel(const int* __restrict__ idx,
                                                     float* __restrict__ enc,
                                                     unsigned int* __restrict__ hist) {
    const int t = threadIdx.x;
    const int j4 = t * 4;
    for (int r = 0; r < 16; ++r) {
        const int n = blockIdx.x*16 + r;
        const int k = idx[n];
        float2 v0 = {0.0f, 0.0f}, v1 = {0.0f, 0.0f};
        if (k == j4)     v0.x = 1.0f;
        if (k == j4 + 1) v0.y = 1.0f;
        if (k == j4 + 2) v1.x = 1.0f;
        if (k == j4 + 3) v1.y = 1.0f;
        float* row = enc + (size_t)n * KKE;
        *(float2*)&row[j4]     = v0;
        *(float2*)&row[j4 + 2] = v1;
        if (t == 0) atomicAdd(&hist[k], 1u);
    }
}

// ---------------- Kernel 6: out = gather(e), loss partials
__global__ __launch_bounds__(256) void out_loss_kernel(const float* __restrict__ inp,
                                                       const float* __restrict__ embT,
                                                       const int* __restrict__ idx,
                                                       float* __restrict__ out,
                                                       float* __restrict__ lossacc) {
    const int t = threadIdx.x;
    const size_t stride = (size_t)gridDim.x * 256;
    float lsum = 0.0f;
    for (size_t m = (size_t)blockIdx.x * 256 + t; m < (size_t)OUT_ELE; m += stride) {
        int hw = (int)(m & 1023);
        int c  = (int)((m >> 10) & 255);
        int b  = (int)(m >> 18);
        int k  = idx[b*HWN + hw];
        float e = embT[(size_t)c*KKE + k];
        float x = inp[m];
        out[m] = e;
        float df = e - x;
        lsum += df * df;
    }
    #pragma unroll
    for (int off = 32; off; off >>= 1) lsum += __shfl_down(lsum, off);
    __shared__ float wred[4];
    const int wave = t >> 6, lane = t & 63;
    if (lane == 0) wred[wave] = lsum;
    __syncthreads();
    if (t == 0) atomicAdd(lossacc, wred[0] + wred[1] + wred[2] + wred[3]);
}

// ---------------- Kernel 7: finalize
__global__ __launch_bounds__(1024) void final_kernel(const unsigned int* __restrict__ hist,
                                                     const float* __restrict__ lossacc,
                                                     float* __restrict__ d_out) {
    const int t = threadIdx.x;
    float p = (float)hist[t] * (1.0f / 65536.0f);
    float v = p * logf(p + 1e-10f);
    #pragma unroll
    for (int off = 32; off; off >>= 1) v += __shfl_down(v, off);
    __shared__ float wred[16];
    const int wave = t >> 6, lane = t & 63;
    if (lane == 0) wred[wave] = v;
    __syncthreads();
    if (t == 0) {
        float s = 0.0f;
        #pragma unroll
        for (int i = 0; i < 16; ++i) s += wred[i];
        d_out[PERP_OFF] = expf(-s);
        d_out[LOSS_OFF] = 1.25f * (*lossacc) * (1.0f / (float)OUT_ELE);
    }
}

extern "C" void kernel_launch(void* const* d_in, const int* in_sizes, int n_in,
                              void* d_out, int out_size, void* d_ws, size_t ws_size,
                              hipStream_t stream) {
    (void)in_sizes; (void)n_in; (void)out_size; (void)ws_size;
    const float* inp = (const float*)d_in[0];
    const float* emb = (const float*)d_in[1];
    float* out = (float*)d_out;
    char* ws = (char*)d_ws;
    int*          idx     = (int*)(ws + WS_IDX);
    float*        anorm   = (float*)(ws + WS_ANORM);
    unsigned int* hist    = (unsigned int*)(ws + WS_HIST);
    float*        bnorm   = (float*)(ws + WS_BNORM);
    float*        misc    = (float*)(ws + WS_MISC);
    int*          list    = (int*)(ws + WS_LIST);
    float*        embT    = (float*)(ws + WS_EMBT);
    short*        ehi     = (short*)(ws + WS_EHI);
    short*        elo     = (short*)(ws + WS_ELO);
    float*        cd1     = (float*)(ws + WS_CD1);
    int*          ck1     = (int*)(ws + WS_CK1);
    float*        cd2     = (float*)(ws + WS_CD2);
    int*          counter = ((int*)misc) + 1;

    prep_kernel<<<dim3(KKE), dim3(256), 0, stream>>>(emb, embT, bnorm, ehi, elo, hist, misc);
    anorm_kernel<<<dim3(4, BB), dim3(256), 0, stream>>>(inp, anorm);
    argmin_mfma<<<dim3(512, 8), dim3(256), 0, stream>>>(inp, ehi, elo, anorm, bnorm, cd1, ck1, cd2);
    reduce_kernel<<<dim3(256), dim3(256), 0, stream>>>(cd1, ck1, cd2, idx, list, counter);
    rescore_kernel<<<dim3(512), dim3(256), 0, stream>>>(inp, embT, anorm, bnorm, list, counter, idx);
    onehot_kernel<<<dim3(4096), dim3(256), 0, stream>>>(idx, out + ENC_OFF, hist);
    out_loss_kernel<<<dim3(4096), dim3(256), 0, stream>>>(inp, embT, idx, out + OUT_OFF, misc);
    final_kernel<<<dim3(1), dim3(1024), 0, stream>>>(hist, misc, out);
}